// Round 14
// baseline (140.403 us; speedup 1.0000x reference)
//
#include <hip/hip_runtime.h>
#include <stdint.h>

#define Tdim 2048
#define Cdim 1024
#define C3   3072

typedef __attribute__((ext_vector_type(8))) short s16x8;
typedef __attribute__((ext_vector_type(4))) unsigned short u16x4;
typedef __attribute__((ext_vector_type(2))) float f32x2;
typedef __attribute__((ext_vector_type(4))) float f32x4;
typedef __attribute__((ext_vector_type(16))) float f32x16;
typedef __attribute__((ext_vector_type(4))) int i32x4;

__device__ __forceinline__ unsigned short f2bf(float f) {
  uint32_t u = __float_as_uint(f);
  return (unsigned short)((u + 0x7FFFu + ((u >> 16) & 1u)) >> 16);
}
__device__ __forceinline__ float bf2f(unsigned short s) {
  return __uint_as_float(((uint32_t)s) << 16);
}
__device__ __forceinline__ uint32_t cvtpk(float lo, float hi) {
  uint32_t r;
  asm("v_cvt_pk_bf16_f32 %0, %1, %2" : "=v"(r) : "v"(lo), "v"(hi));
  return r;
}
__device__ __forceinline__ float exp2v(float x) {
  float r;
  asm("v_exp_f32 %0, %1" : "=v"(r) : "v"(x));
  return r;
}
// async global->LDS, 16B per lane; dest = wave-uniform base + lane*16
typedef __attribute__((address_space(3))) unsigned char lds_uc;
typedef __attribute__((address_space(1))) const unsigned char glb_uc;
__device__ __forceinline__ void gload16(const void* g, void* l) {
  __builtin_amdgcn_global_load_lds((glb_uc*)g, (lds_uc*)l, 16, 0, 0);
}
#define SBAR()  __builtin_amdgcn_s_barrier()
#define SCHED0() __builtin_amdgcn_sched_barrier(0)

// ---------------- fused prep: gn_partial (512) | weight convert (4096) | bias^T (1024) ----------------
__global__ __launch_bounds__(256) void k_prep(const float* __restrict__ x,
                                              float* __restrict__ part,
                                              const float* __restrict__ qkv_w,
                                              const float* __restrict__ proj_w,
                                              unsigned short* __restrict__ wqkv,
                                              unsigned short* __restrict__ wproj,
                                              const float* __restrict__ qk_bias,
                                              unsigned short* __restrict__ biasT) {
  __shared__ float r1[4], r2[4];
  __shared__ unsigned short L[64][65];
  int bid = blockIdx.x;
  int u = threadIdx.x;
  if (bid < 512) {
    int bg = bid >> 3, tc = bid & 7;
    const float* xp = x + ((size_t)(bg >> 5) * Cdim + (size_t)(bg & 31) * 32) * Tdim + tc * 256;
    float s1 = 0.f, s2 = 0.f;
#pragma unroll
    for (int i = 0; i < 32; ++i) {
      int e = u + i * 256;
      float v = xp[(size_t)(e >> 8) * Tdim + (e & 255)];
      s1 += v; s2 += v * v;
    }
    for (int m = 1; m < 64; m <<= 1) { s1 += __shfl_xor(s1, m); s2 += __shfl_xor(s2, m); }
    int w = u >> 6;
    if ((u & 63) == 0) { r1[w] = s1; r2[w] = s2; }
    __syncthreads();
    if (u == 0) {
      part[bid * 2]     = r1[0] + r1[1] + r1[2] + r1[3];
      part[bid * 2 + 1] = r2[0] + r2[1] + r2[2] + r2[3];
    }
  } else if (bid < 512 + 4096) {
    const int n0 = 3072 * 1024 / 4;
    int i = (bid - 512) * 256 + u;
    const float* in = qkv_w;
    unsigned short* out = wqkv;
    if (i >= n0) { i -= n0; in = proj_w; out = wproj; }
    f32x4 v = *(const f32x4*)(in + (size_t)i * 4);
    u16x4 o;
    o[0] = f2bf(v[0]); o[1] = f2bf(v[1]); o[2] = f2bf(v[2]); o[3] = f2bf(v[3]);
    *(u16x4*)(out + (size_t)i * 4) = o;
  } else {
    const float LOG2E = 1.4426950408889634f;
    int idx = bid - 4608;
    int bs0 = (idx & 31) * 64;
    int bt0 = (idx >> 5) * 64;
    int tl = u >> 2, c0 = (u & 3) * 16;
    const float* ip = qk_bias + (size_t)(bt0 + tl) * Tdim + bs0 + c0;
#pragma unroll
    for (int i = 0; i < 16; ++i) L[tl][c0 + i] = f2bf(ip[i] * LOG2E);
    __syncthreads();
    unsigned short* op = biasT + (size_t)(bs0 + tl) * Tdim + bt0 + c0;
#pragma unroll
    for (int i = 0; i < 16; i += 4) {
      u16x4 o;
      o[0] = L[c0 + i][tl]; o[1] = L[c0 + i + 1][tl];
      o[2] = L[c0 + i + 2][tl]; o[3] = L[c0 + i + 3][tl];
      *(u16x4*)(op + i) = o;
    }
  }
}

__global__ void k_gn_final(const float* __restrict__ part, float* __restrict__ stats) {
  int bg = threadIdx.x;             // 64 threads
  float s1 = 0.f, s2 = 0.f;
  for (int j = 0; j < 8; ++j) { s1 += part[(bg * 8 + j) * 2]; s2 += part[(bg * 8 + j) * 2 + 1]; }
  const float inv = 1.f / 65536.f;
  float mean = s1 * inv;
  float var = s2 * inv - mean * mean;
  stats[bg * 2] = mean;
  stats[bg * 2 + 1] = rsqrtf(var + 1e-5f);
}

// ---------------- GroupNorm normalize + transpose -> xn_T (B,T,C) bf16 ----------------
__global__ __launch_bounds__(256) void k_gn_norm(const float* __restrict__ x,
                                                 const float* __restrict__ scale,
                                                 const float* __restrict__ bias,
                                                 const float* __restrict__ stats,
                                                 unsigned short* __restrict__ xnT) {
  int ti = blockIdx.x;              // T/64
  int g  = blockIdx.y;              // 32
  int b  = blockIdx.z;              // 2
  int u  = threadIdx.x;
  int bg = b * 32 + g;
  float mean = stats[bg * 2], rstd = stats[bg * 2 + 1];
  __shared__ float L[32][65];
  int c_loc = u >> 3, tc = (u & 7) * 8;
  int cg = g * 32 + c_loc;
  const float* xp = x + ((size_t)b * Cdim + cg) * Tdim + ti * 64 + tc;
  float sc = scale[cg] * rstd;
  float bi = bias[cg] - mean * sc;  // xn = x*sc + bi
#pragma unroll
  for (int i = 0; i < 8; ++i) L[c_loc][tc + i] = xp[i] * sc + bi;
  __syncthreads();
  int t_loc = u >> 2, cc = (u & 3) * 8;
  s16x8 ov;
#pragma unroll
  for (int i = 0; i < 8; ++i) ov[i] = (short)f2bf(L[cc + i][t_loc]);
  *(s16x8*)&xnT[((size_t)b * Tdim + ti * 64 + t_loc) * Cdim + g * 32 + cc] = ov;
}

// ---------------- QKV GEMM: 256x256 tile, BK=64, counted-vmcnt 2-deep pipeline ----------------
// A = xnT flattened (4096 x 1024), B = wqkv (3072 x 1024). 512 thr = 8 waves (2m x 4n).
// LDS [256][64] shorts per buffer, XOR-swizzled: col16' = col16 ^ (row&7), applied on
// BOTH the pre-swizzled global source (linear gload_lds dest) and the ds_read (rule #21).
__global__ __launch_bounds__(512, 2) void k_qkv(const unsigned short* __restrict__ A,
                                                const unsigned short* __restrict__ Bw,
                                                const float* __restrict__ bias,
                                                unsigned short* __restrict__ outT) {
  const int K = 1024, N = 3072;
  int lin = blockIdx.x;                    // [0,192)
  int k8 = lin & 7, j = lin >> 3;          // XCD, intra index [0,24)
  int mt = (k8 >> 1) * 4 + j / 6;          // [0,16)
  int nt = (k8 & 1) * 6 + j % 6;           // [0,12)
  int m0 = mt * 256, n0 = nt * 256;
  int tid = threadIdx.x;
  int lane = tid & 63, w = tid >> 6;
  int wm = (w >> 2) * 128, wn = (w & 3) * 64;
  int lr = lane & 15, lq = lane >> 4;

  __shared__ __align__(16) short Asl[2][256 * 64];   // 64KB
  __shared__ __align__(16) short Bsl[2][256 * 64];   // 64KB

  // staging geometry: thread t, chunk i: row = i*64 + (t>>3), src col16 = (t&7)^(row&7)
  int sr8 = tid >> 3;
  int sc_base = tid & 7;

  auto stage = [&](int ks, int buf) {
#pragma unroll
    for (int i = 0; i < 4; ++i) {
      int row = i * 64 + sr8;
      int scol = ((sc_base ^ (row & 7)) * 8);
      gload16(A + (size_t)(m0 + row) * K + ks * 64 + scol,
              (char*)&Asl[buf][0] + i * 8192 + tid * 16);
    }
#pragma unroll
    for (int i = 0; i < 4; ++i) {
      int row = i * 64 + sr8;
      int scol = ((sc_base ^ (row & 7)) * 8);
      gload16(Bw + (size_t)(n0 + row) * K + ks * 64 + scol,
              (char*)&Bsl[buf][0] + i * 8192 + tid * 16);
    }
  };

  f32x4 acc[8][4] = {};

  stage(0, 0);
  stage(1, 1);
  asm volatile("s_waitcnt vmcnt(8)" ::: "memory");   // own buf0 loads landed
  SCHED0(); SBAR(); SCHED0();

  for (int k = 0; k < 16; ++k) {
    int c = k & 1;
    const short* Al = &Asl[c][0];
    const short* Bl = &Bsl[c][0];
    // ---- compute K-step k (64 MFMA) ----
#pragma unroll
    for (int kh = 0; kh < 2; ++kh) {
      s16x8 af[8], bfr[4];
#pragma unroll
      for (int mf = 0; mf < 8; ++mf) {
        int row = wm + mf * 16 + lr;
        af[mf] = *(const s16x8*)((const char*)Al + row * 128 + (((kh * 4 + lq) ^ (row & 7)) * 16));
      }
#pragma unroll
      for (int nf = 0; nf < 4; ++nf) {
        int row = wn + nf * 16 + lr;
        bfr[nf] = *(const s16x8*)((const char*)Bl + row * 128 + (((kh * 4 + lq) ^ (row & 7)) * 16));
      }
      __builtin_amdgcn_s_setprio(1);
#pragma unroll
      for (int mf = 0; mf < 8; ++mf)
#pragma unroll
        for (int nf = 0; nf < 4; ++nf)
          acc[mf][nf] = __builtin_amdgcn_mfma_f32_16x16x32_bf16(af[mf], bfr[nf], acc[mf][nf], 0, 0, 0);
      __builtin_amdgcn_s_setprio(0);
    }
    // ---- all reads of buf c done -> safe to restage it ----
    asm volatile("s_waitcnt lgkmcnt(0)" ::: "memory");
    SCHED0(); SBAR(); SCHED0();
    if (k + 2 < 16) {
      stage(k + 2, c);                                  // 8 loads in flight
      asm volatile("s_waitcnt vmcnt(8)" ::: "memory");  // k+1's loads landed (own)
    } else {
      asm volatile("s_waitcnt vmcnt(0)" ::: "memory");
    }
    SCHED0(); SBAR(); SCHED0();                         // k+1 ready for all waves
  }

  // ---- epilogue: bias + store bf16 ----
#pragma unroll
  for (int nf = 0; nf < 4; ++nf) {
    int col = n0 + wn + nf * 16 + lr;
    float bv = bias[col];
#pragma unroll
    for (int mf = 0; mf < 8; ++mf) {
      int rowf = m0 + wm + mf * 16 + lq * 4;
#pragma unroll
      for (int j2 = 0; j2 < 4; ++j2)
        outT[(size_t)(rowf + j2) * N + col] = f2bf(acc[mf][nf][j2] + bv);
    }
  }
}

// ---------------- proj GEMM + residual (m97 structure, BK=32) + XCD-chunked swizzle ----------------
__global__ __launch_bounds__(256) void k_proj(const unsigned short* __restrict__ A,
                                              const unsigned short* __restrict__ Bw,
                                              const float* __restrict__ bias,
                                              const unsigned short* __restrict__ xnT,
                                              float* __restrict__ out) {
  const int K = 1024;
  int lin = blockIdx.x + 16 * blockIdx.y;  // [0,512)
  int k8 = lin & 7, j = lin >> 3;          // XCD, intra index [0,64)
  int mt = (k8 >> 1) * 8 + (j >> 3);       // [0,32) m-tile
  int nt = (k8 & 1) * 8 + (j & 7);         // [0,16) n-tile
  int n0 = nt * 64, m0 = mt * 128;
  int tid = threadIdx.x;
  int lane = tid & 63, w = tid >> 6;
  __shared__ __align__(16) short As[128 * 32];   // 8KB
  __shared__ __align__(16) short Bs[64 * 32];    // 4KB
  f32x4 acc[4][2] = {};
  int wm = (w & 1) * 64, wn = (w >> 1) * 32;
  int lr = lane & 15, lq = lane >> 4;
  int srow = w * 16 + (lane >> 2);
  int scol = (lane & 3) * 8;

  for (int k0 = 0; k0 < K; k0 += 32) {
    __syncthreads();
#pragma unroll
    for (int ch = 0; ch < 2; ++ch)
      gload16(A + (size_t)(m0 + srow + ch * 64) * K + k0 + scol,
              (char*)As + w * 1024 + ch * 4096);
    gload16(Bw + (size_t)(n0 + srow) * K + k0 + scol, (char*)Bs + w * 1024);
    __syncthreads();
    s16x8 af[4], bfr[2];
#pragma unroll
    for (int m = 0; m < 4; ++m) af[m] = *(const s16x8*)&As[(wm + m * 16 + lr) * 32 + lq * 8];
#pragma unroll
    for (int n = 0; n < 2; ++n) bfr[n] = *(const s16x8*)&Bs[(wn + n * 16 + lr) * 32 + lq * 8];
#pragma unroll
    for (int m = 0; m < 4; ++m)
#pragma unroll
      for (int n = 0; n < 2; ++n)
        acc[m][n] = __builtin_amdgcn_mfma_f32_16x16x32_bf16(af[m], bfr[n], acc[m][n], 0, 0, 0);
  }
#pragma unroll
  for (int n = 0; n < 2; ++n) {
    int col = n0 + wn + n * 16 + lr;       // output channel o
    float bv = bias[col];
#pragma unroll
    for (int m = 0; m < 4; ++m) {
      int rowb = m0 + wm + m * 16 + lq * 4;   // flattened row b*2048+t
      int bb = rowb >> 11, t = rowb & 2047;
      f32x4 v;
#pragma unroll
      for (int j2 = 0; j2 < 4; ++j2)
        v[j2] = acc[m][n][j2] + bv + bf2f(xnT[(size_t)(rowb + j2) * Cdim + col]);
      *(f32x4*)&out[((size_t)bb * 1024 + col) * Tdim + t] = v;
    }
  }
}

// ---------------- Flash attention (R11 structure); nc==1 blocks self-normalize ----------------
__global__ __launch_bounds__(256, 2) void k_attn(const unsigned short* __restrict__ qkvT,
                                                 const unsigned short* __restrict__ biasT,
                                                 unsigned short* __restrict__ part0,
                                                 unsigned short* __restrict__ part1,
                                                 unsigned short* __restrict__ part2,
                                                 float* __restrict__ ml) {
  int lin = blockIdx.x + 32 * blockIdx.y;  // [0,1024)
  int k8 = lin & 7, j8 = lin >> 3;         // XCD, intra index [0,128)
  int bh = k8 * 4 + (j8 >> 5);             // [0,32)
  int x  = j8 & 31;                        // work tile id [0,32)
  int ti, cc, nc;
  if (x < 15)      { ti = 15 - x / 3;        cc = x - (x / 3) * 3;  nc = 3; }
  else if (x < 27) { int y = x - 15; ti = 10 - (y >> 1); cc = y & 1; nc = 2; }
  else             { ti = 31 - x;            cc = 0;               nc = 1; }
  int nt_tot = 2 * ti + 2;
  int bse = nt_tot / nc, rem = nt_tot - bse * nc;
  int start = cc * bse + (cc < rem ? cc : rem);
  int cnt = bse + (cc < rem ? 1 : 0);

  int b = bh >> 4, h = bh & 15;
  int tid = threadIdx.x, lane = tid & 63, w = tid >> 6;
  int r = lane & 31, hi = lane >> 5;
  int q0 = ti * 128 + w * 32;
  int qg = q0 + r;
  const unsigned short* hb = qkvT + ((size_t)b * Tdim) * C3 + h * 192;
  const unsigned short* bT = biasT + qg;   // column base, stride Tdim
  unsigned short* pout = (cc == 0) ? part0 : (cc == 1) ? part1 : part2;

  __shared__ __align__(16) char Ks[2][8192];   // [s][ch] 64x64 bf16, byte^=(s&7)<<4
  __shared__ __align__(16) char Vt[2][8192];   // [ch][s] 64x64 bf16, byte^=(ch&7)<<4

  s16x8 qf[4];
#pragma unroll
  for (int kb = 0; kb < 4; ++kb) {
    s16x8 raw = *(const s16x8*)(hb + (size_t)qg * C3 + kb * 16 + hi * 8);
#pragma unroll
    for (int j = 0; j < 8; ++j)
      qf[kb][j] = (short)f2bf(bf2f((unsigned short)raw[j]) * 0.18033688011114373f);
  }

  int ksr[2], kcb[2], vsr[2], vc0[2];
#pragma unroll
  for (int p = 0; p < 2; ++p) {
    int u = tid + p * 256;
    ksr[p] = u >> 3; kcb[p] = u & 7;
    vsr[p] = u & 63; vc0[p] = (u >> 6) * 8;
  }
  s16x8 kc[2], vc[2];
  unsigned short bs[2][16];

  auto issue_kv = [&](int s0) {
#pragma unroll
    for (int p = 0; p < 2; ++p) {
      kc[p] = *(const s16x8*)(hb + (size_t)(s0 + ksr[p]) * C3 + 64 + kcb[p] * 8);
      vc[p] = *(const s16x8*)(hb + (size_t)(s0 + vsr[p]) * C3 + 128 + vc0[p]);
    }
  };
  auto issue_bias = [&](int s0) {
#pragma unroll
    for (int st = 0; st < 2; ++st)
#pragma unroll
      for (int e = 0; e < 16; ++e) {
        int s = s0 + st * 32 + (e & 3) + 8 * (e >> 2) + 4 * hi;
        bs[st][e] = bT[(size_t)s * Tdim];
      }
  };

  issue_kv(start * 64);
  issue_bias(start * 64);

  f32x16 oacc[2];
#pragma unroll
  for (int c2 = 0; c2 < 2; ++c2)
#pragma unroll
    for (int e = 0; e < 16; ++e) oacc[c2][e] = 0.f;
  float mrow = -1e30f, lrowv = 0.f;   // mrow in log2 domain

  for (int it = 0; it < cnt; ++it) {
    int s0 = (start + it) * 64;
    int cur = it & 1;
    char* Kc = &Ks[cur][0];
    char* Vc = &Vt[cur][0];
#pragma unroll
    for (int p = 0; p < 2; ++p) {
      *(s16x8*)(Kc + ksr[p] * 128 + ((kcb[p] * 16) ^ ((ksr[p] & 7) << 4))) = kc[p];
#pragma unroll
      for (int i = 0; i < 8; ++i)
        *(short*)(Vc + (vc0[p] + i) * 128 + ((vsr[p] * 2) ^ (((vc0[p] + i) & 7) << 4))) = vc[p][i];
    }
    __syncthreads();
    if (it + 1 < cnt) issue_kv(s0 + 64);

    bool active = (s0 <= q0 + 31);  // wave-uniform, monotone decreasing
    if (active) {
      f32x16 sa[2];
#pragma unroll
      for (int st = 0; st < 2; ++st) {
#pragma unroll
        for (int e = 0; e < 16; ++e) sa[st][e] = bf2f(bs[st][e]);
        int row = st * 32 + r;
        int swz = (row & 7) << 4;
        __builtin_amdgcn_s_setprio(1);
#pragma unroll
        for (int kb = 0; kb < 4; ++kb) {
          s16x8 kf = *(const s16x8*)(Kc + row * 128 + ((kb * 32 + hi * 16) ^ swz));
          sa[st] = __builtin_amdgcn_mfma_f32_32x32x16_bf16(kf, qf[kb], sa[st], 0, 0, 0);
        }
        __builtin_amdgcn_s_setprio(0);
      }
      if (s0 + 63 > q0) {
#pragma unroll
        for (int st = 0; st < 2; ++st)
#pragma unroll
          for (int e = 0; e < 16; ++e) {
            int s = s0 + st * 32 + (e & 3) + 8 * (e >> 2) + 4 * hi;
            sa[st][e] = (s > qg) ? -1e30f : sa[st][e];
          }
      }
      if (it + 1 < cnt && s0 + 64 <= q0 + 31) issue_bias(s0 + 64);
      float t8[8];
#pragma unroll
      for (int e = 0; e < 8; ++e)
        t8[e] = fmaxf(fmaxf(sa[0][e], sa[0][e + 8]), fmaxf(sa[1][e], sa[1][e + 8]));
      float pm = fmaxf(fmaxf(fmaxf(t8[0], t8[1]), fmaxf(t8[2], t8[3])),
                       fmaxf(fmaxf(t8[4], t8[5]), fmaxf(t8[6], t8[7])));
      pm = fmaxf(pm, __shfl_xor(pm, 32));
      if (!__all(pm <= mrow + 11.5f)) {
        float mnew = fmaxf(mrow, pm);
        float al = exp2v(mrow - mnew);
        mrow = mnew;
        lrowv *= al;
#pragma unroll
        for (int c2 = 0; c2 < 2; ++c2)
#pragma unroll
          for (int e = 0; e < 16; ++e) oacc[c2][e] *= al;
      }
#pragma unroll
      for (int st = 0; st < 2; ++st)
#pragma unroll
        for (int e = 0; e < 16; ++e) sa[st][e] = exp2v(sa[st][e] - mrow);
      float s8[8];
#pragma unroll
      for (int e = 0; e < 8; ++e)
        s8[e] = (sa[0][e] + sa[0][e + 8]) + (sa[1][e] + sa[1][e + 8]);
      float rsum = ((s8[0] + s8[1]) + (s8[2] + s8[3])) + ((s8[4] + s8[5]) + (s8[6] + s8[7]));
      rsum += __shfl_xor(rsum, 32);
      lrowv += rsum;

      s16x8 pfr[4];
#pragma unroll
      for (int sblk = 0; sblk < 4; ++sblk) {
        const int st = sblk >> 1, sb = sblk & 1;
        uint32_t a0 = cvtpk(sa[st][sb * 8 + 0], sa[st][sb * 8 + 1]);
        uint32_t a1 = cvtpk(sa[st][sb * 8 + 2], sa[st][sb * 8 + 3]);
        uint32_t b0 = cvtpk(sa[st][sb * 8 + 4], sa[st][sb * 8 + 5]);
        uint32_t b1 = cvtpk(sa[st][sb * 8 + 6], sa[st][sb * 8 + 7]);
        uint32_t xa0 = (uint32_t)__shfl_xor((int)a0, 32);
        uint32_t xa1 = (uint32_t)__shfl_xor((int)a1, 32);
        uint32_t xb0 = (uint32_t)__shfl_xor((int)b0, 32);
        uint32_t xb1 = (uint32_t)__shfl_xor((int)b1, 32);
        union { i32x4 i; s16x8 s; } u;
        u.i[0] = (int)(hi ? xb0 : a0);
        u.i[1] = (int)(hi ? xb1 : a1);
        u.i[2] = (int)(hi ? b0 : xa0);
        u.i[3] = (int)(hi ? b1 : xa1);
        pfr[sblk] = u.s;
      }
      __builtin_amdgcn_s_setprio(1);
#pragma unroll
      for (int c2 = 0; c2 < 2; ++c2) {
        int row = c2 * 32 + r;
        int swz = (row & 7) << 4;
#pragma unroll
        for (int sblk = 0; sblk < 4; ++sblk) {
          s16x8 vf = *(const s16x8*)(Vc + row * 128 + ((sblk * 32 + hi * 16) ^ swz));
          oacc[c2] = __builtin_amdgcn_mfma_f32_32x32x16_bf16(vf, pfr[sblk], oacc[c2], 0, 0, 0);
        }
      }
      __builtin_amdgcn_s_setprio(0);
    }
  }

  float normf = (nc == 1) ? (1.0f / lrowv) : 1.0f;
  unsigned short* ob = pout + ((size_t)b * Tdim + qg) * Cdim + h * 64;
#pragma unroll
  for (int c2 = 0; c2 < 2; ++c2)
#pragma unroll
    for (int rg = 0; rg < 4; ++rg) {
      u16x4 o;
#pragma unroll
      for (int j = 0; j < 4; ++j) o[j] = f2bf(oacc[c2][rg * 4 + j] * normf);
      *(u16x4*)(ob + c2 * 32 + rg * 8 + 4 * hi) = o;
    }
  if (hi == 0 && nc > 1)
    *(f32x2*)(ml + ((size_t)(cc * 32 + bh) * Tdim + qg) * 2) = f32x2{mrow, lrowv};
}

// ---------------- merge chunks (nc==1 rows already final; early exit) ----------------
__global__ __launch_bounds__(256) void k_merge(unsigned short* __restrict__ part0,
                                               const unsigned short* __restrict__ part1,
                                               const unsigned short* __restrict__ part2,
                                               const float* __restrict__ ml) {
  int idx = blockIdx.x * 256 + threadIdx.x;  // (bh, q, ch8)
  int ch8 = idx & 7;
  int q = (idx >> 3) & 2047;
  int bh = idx >> 14;
  int b = bh >> 4, h = bh & 15;
  int ti = q >> 7;
  int nc = (ti >= 11) ? 3 : (ti >= 5) ? 2 : 1;
  if (nc == 1) return;               // attn wrote normalized output directly
  size_t off = ((size_t)b * Tdim + q) * Cdim + h * 64 + ch8 * 8;
  s16x8 o0 = *(const s16x8*)(part0 + off);
  f32x2 ml0 = *(const f32x2*)(ml + ((size_t)bh * Tdim + q) * 2);
  f32x2 ml1 = *(const f32x2*)(ml + ((size_t)(32 + bh) * Tdim + q) * 2);
  s16x8 o1 = *(const s16x8*)(part1 + off);
  float m = fmaxf(ml0[0], ml1[0]);
  f32x2 ml2;
  s16x8 o2;
  if (nc == 3) {
    ml2 = *(const f32x2*)(ml + ((size_t)(64 + bh) * Tdim + q) * 2);
    o2 = *(const s16x8*)(part2 + off);
    m = fmaxf(m, ml2[0]);
  }
  float e0 = exp2f(ml0[0] - m), e1 = exp2f(ml1[0] - m);
  float den = ml0[1] * e0 + ml1[1] * e1;
  float e2 = 0.f;
  if (nc == 3) { e2 = exp2f(ml2[0] - m); den += ml2[1] * e2; }
  float inv = 1.0f / den;
  float w0 = e0 * inv, w1 = e1 * inv, w2 = e2 * inv;
  s16x8 o;
#pragma unroll
  for (int i = 0; i < 8; ++i) {
    float v = bf2f((unsigned short)o0[i]) * w0 + bf2f((unsigned short)o1[i]) * w1;
    if (nc == 3) v += bf2f((unsigned short)o2[i]) * w2;
    o[i] = (short)f2bf(v);
  }
  *(s16x8*)(part0 + off) = o;
}

extern "C" void kernel_launch(void* const* d_in, const int* in_sizes, int n_in,
                              void* d_out, int out_size, void* d_ws, size_t ws_size,
                              hipStream_t stream) {
  const float* x        = (const float*)d_in[0];
  // d_in[1] = mask (bool tril) — causality applied analytically, ignored
  const float* qk_bias  = (const float*)d_in[2];
  const float* gn_scale = (const float*)d_in[3];
  const float* gn_bias  = (const float*)d_in[4];
  const float* qkv_w    = (const float*)d_in[5];
  const float* qkv_b    = (const float*)d_in[6];
  const float* proj_w   = (const float*)d_in[7];
  const float* proj_b   = (const float*)d_in[8];
  float* out = (float*)d_out;

  char* ws = (char*)d_ws;
  unsigned short* xnT   = (unsigned short*)(ws);                      //  8 MiB (B,T,C)
  unsigned short* qkvT  = (unsigned short*)(ws + ( 8ull << 20));      // 24 MiB (B,T,3C)
  unsigned short* aT    = (unsigned short*)(ws + (32ull << 20));      //  8 MiB part0 / aT
  unsigned short* part1 = (unsigned short*)(ws + (40ull << 20));      //  8 MiB (aliases wqkv, lifetime-disjoint)
  unsigned short* wqkv  = (unsigned short*)(ws + (40ull << 20));      //  6 MiB (3C,C) — dead before attn
  unsigned short* wproj = (unsigned short*)(ws + (48ull << 20));      //  2 MiB (C,C)
  float*          ml    = (float*)(ws + (50ull << 20));               //  1.5 MiB (3,32,T,2)
  float* part  = (float*)(ws + (52ull << 20));                        //  4 KiB
  float* stats = (float*)(ws + (52ull << 20) + 8192);                 //  512 B
  // d_out (16 MiB) doubles as scratch: biasT (first 8 MiB) + part2 (second 8 MiB);
  // both fully written before read, fully overwritten by k_proj. Deterministic.
  unsigned short* biasT = (unsigned short*)d_out;
  unsigned short* part2 = (unsigned short*)d_out + (4ull << 20);      // 8 MiB offset in shorts

  // fused prep: gn partial sums | weight converts | bias transpose
  k_prep<<<5632, 256, 0, stream>>>(x, part, qkv_w, proj_w, wqkv, wproj, qk_bias, biasT);
  k_gn_final<<<1, 64, 0, stream>>>(part, stats);
  k_gn_norm<<<dim3(32, 32, 2), 256, 0, stream>>>(x, gn_scale, gn_bias, stats, xnT);

  // QKV: flattened M=4096, N=3072, K=1024; 256^2 tiles, counted-vmcnt pipeline
  k_qkv<<<192, 512, 0, stream>>>(xnT, wqkv, qkv_b, qkvT);
  // attention, variable split-KV: grid (32 = 15+12+5 blocks, bh)
  k_attn<<<dim3(32, 32), 256, 0, stream>>>(qkvT, biasT, aT, part1, part2, ml);
  k_merge<<<2048, 256, 0, stream>>>(aT, part1, part2, ml);
  // proj + residual: flattened M=4096, N=1024, K=1024, tile 128x64
  k_proj<<<dim3(16, 32), 256, 0, stream>>>(aT, wproj, proj_b, xnT, out);
}

// Round 15
// 136.373 us; speedup vs baseline: 1.0296x; 1.0296x over previous
//
#include <hip/hip_runtime.h>
#include <stdint.h>

#define Tdim 2048
#define Cdim 1024
#define C3   3072

typedef __attribute__((ext_vector_type(8))) short s16x8;
typedef __attribute__((ext_vector_type(4))) unsigned short u16x4;
typedef __attribute__((ext_vector_type(2))) float f32x2;
typedef __attribute__((ext_vector_type(4))) float f32x4;
typedef __attribute__((ext_vector_type(16))) float f32x16;
typedef __attribute__((ext_vector_type(4))) int i32x4;

__device__ __forceinline__ unsigned short f2bf(float f) {
  uint32_t u = __float_as_uint(f);
  return (unsigned short)((u + 0x7FFFu + ((u >> 16) & 1u)) >> 16);
}
__device__ __forceinline__ float bf2f(unsigned short s) {
  return __uint_as_float(((uint32_t)s) << 16);
}
__device__ __forceinline__ uint32_t cvtpk(float lo, float hi) {
  uint32_t r;
  asm("v_cvt_pk_bf16_f32 %0, %1, %2" : "=v"(r) : "v"(lo), "v"(hi));
  return r;
}
__device__ __forceinline__ float exp2v(float x) {
  float r;
  asm("v_exp_f32 %0, %1" : "=v"(r) : "v"(x));
  return r;
}
// async global->LDS, 16B per lane; dest = wave-uniform base + lane*16
typedef __attribute__((address_space(3))) unsigned char lds_uc;
typedef __attribute__((address_space(1))) const unsigned char glb_uc;
__device__ __forceinline__ void gload16(const void* g, void* l) {
  __builtin_amdgcn_global_load_lds((glb_uc*)g, (lds_uc*)l, 16, 0, 0);
}

// ---------------- fused prep: gn_partial (512) | weight convert (4096) | bias^T (1024) ----------------
__global__ __launch_bounds__(256) void k_prep(const float* __restrict__ x,
                                              float* __restrict__ part,
                                              const float* __restrict__ qkv_w,
                                              const float* __restrict__ proj_w,
                                              unsigned short* __restrict__ wqkv,
                                              unsigned short* __restrict__ wproj,
                                              const float* __restrict__ qk_bias,
                                              unsigned short* __restrict__ biasT) {
  __shared__ float r1[4], r2[4];
  __shared__ unsigned short L[64][65];
  int bid = blockIdx.x;
  int u = threadIdx.x;
  if (bid < 512) {
    int bg = bid >> 3, tc = bid & 7;
    const float* xp = x + ((size_t)(bg >> 5) * Cdim + (size_t)(bg & 31) * 32) * Tdim + tc * 256;
    float s1 = 0.f, s2 = 0.f;
#pragma unroll
    for (int i = 0; i < 32; ++i) {
      int e = u + i * 256;
      float v = xp[(size_t)(e >> 8) * Tdim + (e & 255)];
      s1 += v; s2 += v * v;
    }
    for (int m = 1; m < 64; m <<= 1) { s1 += __shfl_xor(s1, m); s2 += __shfl_xor(s2, m); }
    int w = u >> 6;
    if ((u & 63) == 0) { r1[w] = s1; r2[w] = s2; }
    __syncthreads();
    if (u == 0) {
      part[bid * 2]     = r1[0] + r1[1] + r1[2] + r1[3];
      part[bid * 2 + 1] = r2[0] + r2[1] + r2[2] + r2[3];
    }
  } else if (bid < 512 + 4096) {
    const int n0 = 3072 * 1024 / 4;
    int i = (bid - 512) * 256 + u;
    const float* in = qkv_w;
    unsigned short* out = wqkv;
    if (i >= n0) { i -= n0; in = proj_w; out = wproj; }
    f32x4 v = *(const f32x4*)(in + (size_t)i * 4);
    u16x4 o;
    o[0] = f2bf(v[0]); o[1] = f2bf(v[1]); o[2] = f2bf(v[2]); o[3] = f2bf(v[3]);
    *(u16x4*)(out + (size_t)i * 4) = o;
  } else {
    const float LOG2E = 1.4426950408889634f;
    int idx = bid - 4608;
    int bs0 = (idx & 31) * 64;
    int bt0 = (idx >> 5) * 64;
    int tl = u >> 2, c0 = (u & 3) * 16;
    const float* ip = qk_bias + (size_t)(bt0 + tl) * Tdim + bs0 + c0;
#pragma unroll
    for (int i = 0; i < 16; ++i) L[tl][c0 + i] = f2bf(ip[i] * LOG2E);
    __syncthreads();
    unsigned short* op = biasT + (size_t)(bs0 + tl) * Tdim + bt0 + c0;
#pragma unroll
    for (int i = 0; i < 16; i += 4) {
      u16x4 o;
      o[0] = L[c0 + i][tl]; o[1] = L[c0 + i + 1][tl];
      o[2] = L[c0 + i + 2][tl]; o[3] = L[c0 + i + 3][tl];
      *(u16x4*)(op + i) = o;
    }
  }
}

__global__ void k_gn_final(const float* __restrict__ part, float* __restrict__ stats) {
  int bg = threadIdx.x;             // 64 threads
  float s1 = 0.f, s2 = 0.f;
  for (int j = 0; j < 8; ++j) { s1 += part[(bg * 8 + j) * 2]; s2 += part[(bg * 8 + j) * 2 + 1]; }
  const float inv = 1.f / 65536.f;
  float mean = s1 * inv;
  float var = s2 * inv - mean * mean;
  stats[bg * 2] = mean;
  stats[bg * 2 + 1] = rsqrtf(var + 1e-5f);
}

// ---------------- GroupNorm normalize + transpose -> xn_T (B,T,C) bf16 ----------------
__global__ __launch_bounds__(256) void k_gn_norm(const float* __restrict__ x,
                                                 const float* __restrict__ scale,
                                                 const float* __restrict__ bias,
                                                 const float* __restrict__ stats,
                                                 unsigned short* __restrict__ xnT) {
  int ti = blockIdx.x;              // T/64
  int g  = blockIdx.y;              // 32
  int b  = blockIdx.z;              // 2
  int u  = threadIdx.x;
  int bg = b * 32 + g;
  float mean = stats[bg * 2], rstd = stats[bg * 2 + 1];
  __shared__ float L[32][65];
  int c_loc = u >> 3, tc = (u & 7) * 8;
  int cg = g * 32 + c_loc;
  const float* xp = x + ((size_t)b * Cdim + cg) * Tdim + ti * 64 + tc;
  float sc = scale[cg] * rstd;
  float bi = bias[cg] - mean * sc;  // xn = x*sc + bi
#pragma unroll
  for (int i = 0; i < 8; ++i) L[c_loc][tc + i] = xp[i] * sc + bi;
  __syncthreads();
  int t_loc = u >> 2, cc = (u & 3) * 8;
  s16x8 ov;
#pragma unroll
  for (int i = 0; i < 8; ++i) ov[i] = (short)f2bf(L[cc + i][t_loc]);
  *(s16x8*)&xnT[((size_t)b * Tdim + ti * 64 + t_loc) * Cdim + g * 32 + cc] = ov;
}

// ---------------- QKV GEMM (m97 structure, BK=32, R11/R13-proven) + XCD-chunked swizzle ----------------
__global__ __launch_bounds__(256) void k_qkv(const unsigned short* __restrict__ A,
                                             const unsigned short* __restrict__ Bw,
                                             const float* __restrict__ bias,
                                             unsigned short* __restrict__ outT) {
  const int M = 2048, N = 3072, K = 1024;
  int lin = blockIdx.x + 24 * (blockIdx.y + 16 * blockIdx.z);  // [0,768)
  int k8 = lin & 7, j = lin >> 3;          // XCD id, intra-XCD index
  int bb = k8 >> 2;                        // batch
  int q = k8 & 3;
  int by = (q >> 1) * 8 + j / 12;          // [0,16)
  int bx = (q & 1) * 12 + j % 12;          // [0,24)
  int tid = threadIdx.x;
  int lane = tid & 63, w = tid >> 6;
  int m0 = by * 128, n0 = bx * 128;
  const unsigned short* Ab = A + (size_t)bb * M * K;
  __shared__ __align__(16) short As[128 * 32];
  __shared__ __align__(16) short Bs[128 * 32];
  f32x4 acc[4][4] = {};
  int wm = (w >> 1) * 64, wn = (w & 1) * 64;
  int lr = lane & 15, lq = lane >> 4;
  int srow = w * 16 + (lane >> 2);       // staging row within 64-row chunk
  int scol = (lane & 3) * 8;             // staging col (elements)

  for (int k0 = 0; k0 < K; k0 += 32) {
    __syncthreads();
#pragma unroll
    for (int ch = 0; ch < 2; ++ch) {
      gload16(Ab + (size_t)(m0 + srow + ch * 64) * K + k0 + scol,
              (char*)As + w * 1024 + ch * 4096);
      gload16(Bw + (size_t)(n0 + srow + ch * 64) * K + k0 + scol,
              (char*)Bs + w * 1024 + ch * 4096);
    }
    __syncthreads();
    s16x8 af[4], bfr[4];
#pragma unroll
    for (int m = 0; m < 4; ++m) af[m] = *(const s16x8*)&As[(wm + m * 16 + lr) * 32 + lq * 8];
#pragma unroll
    for (int n = 0; n < 4; ++n) bfr[n] = *(const s16x8*)&Bs[(wn + n * 16 + lr) * 32 + lq * 8];
#pragma unroll
    for (int m = 0; m < 4; ++m)
#pragma unroll
      for (int n = 0; n < 4; ++n)
        acc[m][n] = __builtin_amdgcn_mfma_f32_16x16x32_bf16(af[m], bfr[n], acc[m][n], 0, 0, 0);
  }
#pragma unroll
  for (int n = 0; n < 4; ++n) {
    int col = n0 + wn + n * 16 + lr;
    float bv = bias[col];
#pragma unroll
    for (int m = 0; m < 4; ++m) {
      int rowb = m0 + wm + m * 16 + lq * 4;
#pragma unroll
      for (int j2 = 0; j2 < 4; ++j2)
        outT[((size_t)bb * M + rowb + j2) * N + col] = f2bf(acc[m][n][j2] + bv);
    }
  }
}

// ---------------- proj GEMM + residual (m97 structure, BK=32) + XCD-chunked swizzle ----------------
__global__ __launch_bounds__(256) void k_proj(const unsigned short* __restrict__ A,
                                              const unsigned short* __restrict__ Bw,
                                              const float* __restrict__ bias,
                                              const unsigned short* __restrict__ xnT,
                                              float* __restrict__ out) {
  const int K = 1024;
  int lin = blockIdx.x + 16 * blockIdx.y;  // [0,512)
  int k8 = lin & 7, j = lin >> 3;          // XCD, intra index [0,64)
  int mt = (k8 >> 1) * 8 + (j >> 3);       // [0,32) m-tile
  int nt = (k8 & 1) * 8 + (j & 7);         // [0,16) n-tile
  int n0 = nt * 64, m0 = mt * 128;
  int tid = threadIdx.x;
  int lane = tid & 63, w = tid >> 6;
  __shared__ __align__(16) short As[128 * 32];   // 8KB
  __shared__ __align__(16) short Bs[64 * 32];    // 4KB
  f32x4 acc[4][2] = {};
  int wm = (w & 1) * 64, wn = (w >> 1) * 32;
  int lr = lane & 15, lq = lane >> 4;
  int srow = w * 16 + (lane >> 2);
  int scol = (lane & 3) * 8;

  for (int k0 = 0; k0 < K; k0 += 32) {
    __syncthreads();
#pragma unroll
    for (int ch = 0; ch < 2; ++ch)
      gload16(A + (size_t)(m0 + srow + ch * 64) * K + k0 + scol,
              (char*)As + w * 1024 + ch * 4096);
    gload16(Bw + (size_t)(n0 + srow) * K + k0 + scol, (char*)Bs + w * 1024);
    __syncthreads();
    s16x8 af[4], bfr[2];
#pragma unroll
    for (int m = 0; m < 4; ++m) af[m] = *(const s16x8*)&As[(wm + m * 16 + lr) * 32 + lq * 8];
#pragma unroll
    for (int n = 0; n < 2; ++n) bfr[n] = *(const s16x8*)&Bs[(wn + n * 16 + lr) * 32 + lq * 8];
#pragma unroll
    for (int m = 0; m < 4; ++m)
#pragma unroll
      for (int n = 0; n < 2; ++n)
        acc[m][n] = __builtin_amdgcn_mfma_f32_16x16x32_bf16(af[m], bfr[n], acc[m][n], 0, 0, 0);
  }
#pragma unroll
  for (int n = 0; n < 2; ++n) {
    int col = n0 + wn + n * 16 + lr;       // output channel o
    float bv = bias[col];
#pragma unroll
    for (int m = 0; m < 4; ++m) {
      int rowb = m0 + wm + m * 16 + lq * 4;   // flattened row b*2048+t
      int bb = rowb >> 11, t = rowb & 2047;
      f32x4 v;
#pragma unroll
      for (int j2 = 0; j2 < 4; ++j2)
        v[j2] = acc[m][n][j2] + bv + bf2f(xnT[(size_t)(rowb + j2) * Cdim + col]);
      *(f32x4*)&out[((size_t)bb * 1024 + col) * Tdim + t] = v;
    }
  }
}

// ---------------- Flash attention (R11 structure); nc==1 blocks self-normalize ----------------
__global__ __launch_bounds__(256, 2) void k_attn(const unsigned short* __restrict__ qkvT,
                                                 const unsigned short* __restrict__ biasT,
                                                 unsigned short* __restrict__ part0,
                                                 unsigned short* __restrict__ part1,
                                                 unsigned short* __restrict__ part2,
                                                 float* __restrict__ ml) {
  int lin = blockIdx.x + 32 * blockIdx.y;  // [0,1024)
  int k8 = lin & 7, j8 = lin >> 3;         // XCD, intra index [0,128)
  int bh = k8 * 4 + (j8 >> 5);             // [0,32)
  int x  = j8 & 31;                        // work tile id [0,32)
  int ti, cc, nc;
  if (x < 15)      { ti = 15 - x / 3;        cc = x - (x / 3) * 3;  nc = 3; }
  else if (x < 27) { int y = x - 15; ti = 10 - (y >> 1); cc = y & 1; nc = 2; }
  else             { ti = 31 - x;            cc = 0;               nc = 1; }
  int nt_tot = 2 * ti + 2;
  int bse = nt_tot / nc, rem = nt_tot - bse * nc;
  int start = cc * bse + (cc < rem ? cc : rem);
  int cnt = bse + (cc < rem ? 1 : 0);

  int b = bh >> 4, h = bh & 15;
  int tid = threadIdx.x, lane = tid & 63, w = tid >> 6;
  int r = lane & 31, hi = lane >> 5;
  int q0 = ti * 128 + w * 32;
  int qg = q0 + r;
  const unsigned short* hb = qkvT + ((size_t)b * Tdim) * C3 + h * 192;
  const unsigned short* bT = biasT + qg;   // column base, stride Tdim
  unsigned short* pout = (cc == 0) ? part0 : (cc == 1) ? part1 : part2;

  __shared__ __align__(16) char Ks[2][8192];   // [s][ch] 64x64 bf16, byte^=(s&7)<<4
  __shared__ __align__(16) char Vt[2][8192];   // [ch][s] 64x64 bf16, byte^=(ch&7)<<4

  s16x8 qf[4];
#pragma unroll
  for (int kb = 0; kb < 4; ++kb) {
    s16x8 raw = *(const s16x8*)(hb + (size_t)qg * C3 + kb * 16 + hi * 8);
#pragma unroll
    for (int j = 0; j < 8; ++j)
      qf[kb][j] = (short)f2bf(bf2f((unsigned short)raw[j]) * 0.18033688011114373f);
  }

  int ksr[2], kcb[2], vsr[2], vc0[2];
#pragma unroll
  for (int p = 0; p < 2; ++p) {
    int u = tid + p * 256;
    ksr[p] = u >> 3; kcb[p] = u & 7;
    vsr[p] = u & 63; vc0[p] = (u >> 6) * 8;
  }
  s16x8 kc[2], vc[2];
  unsigned short bs[2][16];

  auto issue_kv = [&](int s0) {
#pragma unroll
    for (int p = 0; p < 2; ++p) {
      kc[p] = *(const s16x8*)(hb + (size_t)(s0 + ksr[p]) * C3 + 64 + kcb[p] * 8);
      vc[p] = *(const s16x8*)(hb + (size_t)(s0 + vsr[p]) * C3 + 128 + vc0[p]);
    }
  };
  auto issue_bias = [&](int s0) {
#pragma unroll
    for (int st = 0; st < 2; ++st)
#pragma unroll
      for (int e = 0; e < 16; ++e) {
        int s = s0 + st * 32 + (e & 3) + 8 * (e >> 2) + 4 * hi;
        bs[st][e] = bT[(size_t)s * Tdim];
      }
  };

  issue_kv(start * 64);
  issue_bias(start * 64);

  f32x16 oacc[2];
#pragma unroll
  for (int c2 = 0; c2 < 2; ++c2)
#pragma unroll
    for (int e = 0; e < 16; ++e) oacc[c2][e] = 0.f;
  float mrow = -1e30f, lrowv = 0.f;   // mrow in log2 domain

  for (int it = 0; it < cnt; ++it) {
    int s0 = (start + it) * 64;
    int cur = it & 1;
    char* Kc = &Ks[cur][0];
    char* Vc = &Vt[cur][0];
#pragma unroll
    for (int p = 0; p < 2; ++p) {
      *(s16x8*)(Kc + ksr[p] * 128 + ((kcb[p] * 16) ^ ((ksr[p] & 7) << 4))) = kc[p];
#pragma unroll
      for (int i = 0; i < 8; ++i)
        *(short*)(Vc + (vc0[p] + i) * 128 + ((vsr[p] * 2) ^ (((vc0[p] + i) & 7) << 4))) = vc[p][i];
    }
    __syncthreads();
    if (it + 1 < cnt) issue_kv(s0 + 64);

    bool active = (s0 <= q0 + 31);  // wave-uniform, monotone decreasing
    if (active) {
      f32x16 sa[2];
#pragma unroll
      for (int st = 0; st < 2; ++st) {
#pragma unroll
        for (int e = 0; e < 16; ++e) sa[st][e] = bf2f(bs[st][e]);
        int row = st * 32 + r;
        int swz = (row & 7) << 4;
        __builtin_amdgcn_s_setprio(1);
#pragma unroll
        for (int kb = 0; kb < 4; ++kb) {
          s16x8 kf = *(const s16x8*)(Kc + row * 128 + ((kb * 32 + hi * 16) ^ swz));
          sa[st] = __builtin_amdgcn_mfma_f32_32x32x16_bf16(kf, qf[kb], sa[st], 0, 0, 0);
        }
        __builtin_amdgcn_s_setprio(0);
      }
      if (s0 + 63 > q0) {
#pragma unroll
        for (int st = 0; st < 2; ++st)
#pragma unroll
          for (int e = 0; e < 16; ++e) {
            int s = s0 + st * 32 + (e & 3) + 8 * (e >> 2) + 4 * hi;
            sa[st][e] = (s > qg) ? -1e30f : sa[st][e];
          }
      }
      if (it + 1 < cnt && s0 + 64 <= q0 + 31) issue_bias(s0 + 64);
      float t8[8];
#pragma unroll
      for (int e = 0; e < 8; ++e)
        t8[e] = fmaxf(fmaxf(sa[0][e], sa[0][e + 8]), fmaxf(sa[1][e], sa[1][e + 8]));
      float pm = fmaxf(fmaxf(fmaxf(t8[0], t8[1]), fmaxf(t8[2], t8[3])),
                       fmaxf(fmaxf(t8[4], t8[5]), fmaxf(t8[6], t8[7])));
      pm = fmaxf(pm, __shfl_xor(pm, 32));
      if (!__all(pm <= mrow + 11.5f)) {
        float mnew = fmaxf(mrow, pm);
        float al = exp2v(mrow - mnew);
        mrow = mnew;
        lrowv *= al;
#pragma unroll
        for (int c2 = 0; c2 < 2; ++c2)
#pragma unroll
          for (int e = 0; e < 16; ++e) oacc[c2][e] *= al;
      }
#pragma unroll
      for (int st = 0; st < 2; ++st)
#pragma unroll
        for (int e = 0; e < 16; ++e) sa[st][e] = exp2v(sa[st][e] - mrow);
      float s8[8];
#pragma unroll
      for (int e = 0; e < 8; ++e)
        s8[e] = (sa[0][e] + sa[0][e + 8]) + (sa[1][e] + sa[1][e + 8]);
      float rsum = ((s8[0] + s8[1]) + (s8[2] + s8[3])) + ((s8[4] + s8[5]) + (s8[6] + s8[7]));
      rsum += __shfl_xor(rsum, 32);
      lrowv += rsum;

      s16x8 pfr[4];
#pragma unroll
      for (int sblk = 0; sblk < 4; ++sblk) {
        const int st = sblk >> 1, sb = sblk & 1;
        uint32_t a0 = cvtpk(sa[st][sb * 8 + 0], sa[st][sb * 8 + 1]);
        uint32_t a1 = cvtpk(sa[st][sb * 8 + 2], sa[st][sb * 8 + 3]);
        uint32_t b0 = cvtpk(sa[st][sb * 8 + 4], sa[st][sb * 8 + 5]);
        uint32_t b1 = cvtpk(sa[st][sb * 8 + 6], sa[st][sb * 8 + 7]);
        uint32_t xa0 = (uint32_t)__shfl_xor((int)a0, 32);
        uint32_t xa1 = (uint32_t)__shfl_xor((int)a1, 32);
        uint32_t xb0 = (uint32_t)__shfl_xor((int)b0, 32);
        uint32_t xb1 = (uint32_t)__shfl_xor((int)b1, 32);
        union { i32x4 i; s16x8 s; } u;
        u.i[0] = (int)(hi ? xb0 : a0);
        u.i[1] = (int)(hi ? xb1 : a1);
        u.i[2] = (int)(hi ? b0 : xa0);
        u.i[3] = (int)(hi ? b1 : xa1);
        pfr[sblk] = u.s;
      }
      __builtin_amdgcn_s_setprio(1);
#pragma unroll
      for (int c2 = 0; c2 < 2; ++c2) {
        int row = c2 * 32 + r;
        int swz = (row & 7) << 4;
#pragma unroll
        for (int sblk = 0; sblk < 4; ++sblk) {
          s16x8 vf = *(const s16x8*)(Vc + row * 128 + ((sblk * 32 + hi * 16) ^ swz));
          oacc[c2] = __builtin_amdgcn_mfma_f32_32x32x16_bf16(vf, pfr[sblk], oacc[c2], 0, 0, 0);
        }
      }
      __builtin_amdgcn_s_setprio(0);
    }
  }

  float normf = (nc == 1) ? (1.0f / lrowv) : 1.0f;
  unsigned short* ob = pout + ((size_t)b * Tdim + qg) * Cdim + h * 64;
#pragma unroll
  for (int c2 = 0; c2 < 2; ++c2)
#pragma unroll
    for (int rg = 0; rg < 4; ++rg) {
      u16x4 o;
#pragma unroll
      for (int j = 0; j < 4; ++j) o[j] = f2bf(oacc[c2][rg * 4 + j] * normf);
      *(u16x4*)(ob + c2 * 32 + rg * 8 + 4 * hi) = o;
    }
  if (hi == 0 && nc > 1)
    *(f32x2*)(ml + ((size_t)(cc * 32 + bh) * Tdim + qg) * 2) = f32x2{mrow, lrowv};
}

// ---------------- merge chunks; grid covers only rows q>=640 (ti>=5, nc>=2) ----------------
__global__ __launch_bounds__(256) void k_merge(unsigned short* __restrict__ part0,
                                               const unsigned short* __restrict__ part1,
                                               const unsigned short* __restrict__ part2,
                                               const float* __restrict__ ml) {
  int idx = blockIdx.x * 256 + threadIdx.x;  // (bh, q-640, ch8); 32*1408*8 threads
  int ch8 = idx & 7;
  int qq = (idx >> 3) % 1408;
  int bh = (idx >> 3) / 1408;
  int q = 640 + qq;
  int b = bh >> 4, h = bh & 15;
  int ti = q >> 7;
  int nc = (ti >= 11) ? 3 : 2;
  size_t off = ((size_t)b * Tdim + q) * Cdim + h * 64 + ch8 * 8;
  s16x8 o0 = *(const s16x8*)(part0 + off);
  f32x2 ml0 = *(const f32x2*)(ml + ((size_t)bh * Tdim + q) * 2);
  f32x2 ml1 = *(const f32x2*)(ml + ((size_t)(32 + bh) * Tdim + q) * 2);
  s16x8 o1 = *(const s16x8*)(part1 + off);
  float m = fmaxf(ml0[0], ml1[0]);
  f32x2 ml2;
  s16x8 o2;
  if (nc == 3) {
    ml2 = *(const f32x2*)(ml + ((size_t)(64 + bh) * Tdim + q) * 2);
    o2 = *(const s16x8*)(part2 + off);
    m = fmaxf(m, ml2[0]);
  }
  float e0 = exp2f(ml0[0] - m), e1 = exp2f(ml1[0] - m);
  float den = ml0[1] * e0 + ml1[1] * e1;
  float e2 = 0.f;
  if (nc == 3) { e2 = exp2f(ml2[0] - m); den += ml2[1] * e2; }
  float inv = 1.0f / den;
  float w0 = e0 * inv, w1 = e1 * inv, w2 = e2 * inv;
  s16x8 o;
#pragma unroll
  for (int i = 0; i < 8; ++i) {
    float v = bf2f((unsigned short)o0[i]) * w0 + bf2f((unsigned short)o1[i]) * w1;
    if (nc == 3) v += bf2f((unsigned short)o2[i]) * w2;
    o[i] = (short)f2bf(v);
  }
  *(s16x8*)(part0 + off) = o;
}

extern "C" void kernel_launch(void* const* d_in, const int* in_sizes, int n_in,
                              void* d_out, int out_size, void* d_ws, size_t ws_size,
                              hipStream_t stream) {
  const float* x        = (const float*)d_in[0];
  // d_in[1] = mask (bool tril) — causality applied analytically, ignored
  const float* qk_bias  = (const float*)d_in[2];
  const float* gn_scale = (const float*)d_in[3];
  const float* gn_bias  = (const float*)d_in[4];
  const float* qkv_w    = (const float*)d_in[5];
  const float* qkv_b    = (const float*)d_in[6];
  const float* proj_w   = (const float*)d_in[7];
  const float* proj_b   = (const float*)d_in[8];
  float* out = (float*)d_out;

  char* ws = (char*)d_ws;
  unsigned short* xnT   = (unsigned short*)(ws);                      //  8 MiB (B,T,C)
  unsigned short* qkvT  = (unsigned short*)(ws + ( 8ull << 20));      // 24 MiB (B,T,3C)
  unsigned short* aT    = (unsigned short*)(ws + (32ull << 20));      //  8 MiB part0 / aT
  unsigned short* part1 = (unsigned short*)(ws + (40ull << 20));      //  8 MiB (aliases wqkv, lifetime-disjoint)
  unsigned short* wqkv  = (unsigned short*)(ws + (40ull << 20));      //  6 MiB (3C,C) — dead before attn
  unsigned short* wproj = (unsigned short*)(ws + (48ull << 20));      //  2 MiB (C,C)
  float*          ml    = (float*)(ws + (50ull << 20));               //  1.5 MiB (3,32,T,2)
  float* part  = (float*)(ws + (52ull << 20));                        //  4 KiB
  float* stats = (float*)(ws + (52ull << 20) + 8192);                 //  512 B
  // d_out (16 MiB) doubles as scratch: biasT (first 8 MiB) + part2 (second 8 MiB);
  // both fully written before read, fully overwritten by k_proj. Deterministic.
  unsigned short* biasT = (unsigned short*)d_out;
  unsigned short* part2 = (unsigned short*)d_out + (4ull << 20);      // 8 MiB offset in shorts

  // fused prep: gn partial sums | weight converts | bias transpose
  k_prep<<<5632, 256, 0, stream>>>(x, part, qkv_w, proj_w, wqkv, wproj, qk_bias, biasT);
  k_gn_final<<<1, 64, 0, stream>>>(part, stats);
  k_gn_norm<<<dim3(32, 32, 2), 256, 0, stream>>>(x, gn_scale, gn_bias, stats, xnT);

  // QKV: M=T=2048, N=3C=3072, K=C=1024, batched over B
  k_qkv<<<dim3(24, 16, 2), 256, 0, stream>>>(xnT, wqkv, qkv_b, qkvT);
  // attention, variable split-KV: grid (32 = 15+12+5 blocks, bh)
  k_attn<<<dim3(32, 32), 256, 0, stream>>>(qkvT, biasT, aT, part1, part2, ml);
  // merge only rows q in [640,2048): 32 bh x 1408 q x 8 ch8 / 256 = 1408 blocks
  k_merge<<<1408, 256, 0, stream>>>(aT, part1, part2, ml);
  // proj + residual: flattened M=4096, N=1024, K=1024, tile 128x64
  k_proj<<<dim3(16, 32), 256, 0, stream>>>(aT, wproj, proj_b, xnT, out);
}